// Round 9
// baseline (743.520 us; speedup 1.0000x reference)
//
#include <hip/hip_runtime.h>

typedef unsigned short u16;
typedef __bf16 v8bf __attribute__((ext_vector_type(8)));
typedef float v4f __attribute__((ext_vector_type(4)));
typedef float v16f __attribute__((ext_vector_type(16)));

// ---------- static device workspace ----------
__device__ __align__(256) unsigned char g_ws[180000000];

// ---------- bf16 helpers ----------
__device__ __forceinline__ float bf2f(u16 u) {
    union { unsigned int i; float f; } v; v.i = ((unsigned int)u) << 16; return v.f;
}
__device__ __forceinline__ u16 f2bf(float f) {
    union { float f; unsigned int i; } v; v.f = f;
    unsigned int r = v.i + 0x7FFFu + ((v.i >> 16) & 1u);
    return (u16)(r >> 16);
}
__device__ __forceinline__ float gelu_exact(float x) {
    return 0.5f * x * (1.0f + erff(x * 0.70710678118654752f));
}

// async global->LDS, 16 bytes per lane, dest = uniform base + lane*16
typedef const __attribute__((address_space(1))) void* gas_t;
typedef __attribute__((address_space(3))) void* las_t;
__device__ __forceinline__ void gload16(const u16* g, u16* lds_base_uniform) {
    __builtin_amdgcn_global_load_lds((gas_t)g, (las_t)lds_base_uniform, 16, 0, 0);
}

// ---------- fused f32 -> bf16 conversion of all weight/bias tensors ----------
#define NT 22
struct ConvArgs {
    const float* src[NT];
    unsigned int dstoff[NT];
    int n[NT];
    int cumblk[NT + 1];
};

__global__ __launch_bounds__(256) void conv_all(ConvArgs a, u16* __restrict__ arena) {
    int bid = blockIdx.x;
    int t = 0;
    while (t < NT - 1 && bid >= a.cumblk[t + 1]) t++;
    int base = (bid - a.cumblk[t]) * 2048;
    const float* s = a.src[t];
    u16* d = arena + a.dstoff[t];
    int n = a.n[t];
#pragma unroll
    for (int j = 0; j < 8; j++) {
        int idx = base + j * 256 + threadIdx.x;
        if (idx < n) d[idx] = f2bf(s[idx]);
    }
}

// Wp [i][o][k] -> Wp_p [o][i*256+k]
__global__ __launch_bounds__(256) void permute_wp(
    const u16* __restrict__ src, u16* __restrict__ dst)
{
    int o = blockIdx.x >> 3;
    int i = (blockIdx.x & 7);
    if (i >= 6) return;
    int k = threadIdx.x;
    dst[(long)o * 1536 + i * 256 + k] = src[(long)i * 65536 + o * 256 + k];
}

// ---------- x [B,C,L] f32 -> xT [B*L, C] bf16 ----------
__global__ __launch_bounds__(256) void transpose_f2b(
    const float* __restrict__ in, u16* __restrict__ out, int R, int S)
{
    __shared__ u16 tile[32][33];
    long b = blockIdx.z;
    const float* ip = in + b * (long)R * S;
    u16* op = out + b * (long)R * S;
    int s0 = blockIdx.x * 32, r0 = blockIdx.y * 32;
    int tx = threadIdx.x & 31, ty = threadIdx.x >> 5;
#pragma unroll
    for (int j = 0; j < 4; j++) {
        int r = ty + j * 8;
        tile[r][tx] = f2bf(ip[(long)(r0 + r) * S + s0 + tx]);
    }
    __syncthreads();
#pragma unroll
    for (int j = 0; j < 4; j++) {
        int r = ty + j * 8;
        op[(long)(s0 + r) * R + r0 + tx] = tile[tx][r];
    }
}

// ---------- main GEMM (128x128 tile, BK=64, global_load_lds + XOR swizzle) ----------
// modes: 0 bf16, 1 gelu->bf16, 2 (acc+bias)*aux->bf16, 3 f32 store
__global__ __launch_bounds__(256) void gemm_t(
    const u16* __restrict__ A, int lda, long az,
    const u16* __restrict__ W, int ldw, long wz,
    const u16* __restrict__ bias, long bz_,
    void* __restrict__ out, long oz,
    const u16* __restrict__ W2b, const u16* __restrict__ bias2, void* __restrict__ out2,
    const u16* __restrict__ aux, long xz,
    int Kd, int ldO, int mode)
{
    long z = blockIdx.z;
    if (W2b) {
        if (z == 1) { W = W2b; bias = bias2; out = out2; }
    } else {
        A += z * az; W += z * wz; bias += z * bz_;
        out = (void*)((char*)out + z * oz);
        if (aux) aux += z * xz;
    }

    __shared__ alignas(16) u16 lA[128 * 64];
    __shared__ alignas(16) u16 lW[128 * 64];

    const int tid = threadIdx.x;
    const int wave = tid >> 6, lane = tid & 63;
    const int wm = wave >> 1, wn = wave & 1;
    const int lrow = lane & 15, quad = lane >> 4;
    const int m0 = blockIdx.x * 128;
    const int o0 = blockIdx.y * 128;

    const u16* Ab = A + (long)m0 * lda;
    const u16* Wb = W + (long)o0 * ldw;

    const int slr = lane >> 3;
    const int scp = lane & 7;
    const int ssrc = (scp ^ slr) * 8;

    v4f acc[4][4];
#pragma unroll
    for (int ms = 0; ms < 4; ms++)
#pragma unroll
        for (int ns = 0; ns < 4; ns++)
#pragma unroll
            for (int q = 0; q < 4; q++) acc[ms][ns][q] = 0.0f;

    for (int k0 = 0; k0 < Kd; k0 += 64) {
        __syncthreads();
#pragma unroll
        for (int j = 0; j < 4; j++) {
            int rb = wave * 4 + j;
            int row = rb * 8 + slr;
            gload16(Ab + (long)row * lda + k0 + ssrc, &lA[rb * 512]);
        }
#pragma unroll
        for (int j = 0; j < 4; j++) {
            int rb = wave * 4 + j;
            int row = rb * 8 + slr;
            gload16(Wb + (long)row * ldw + k0 + ssrc, &lW[rb * 512]);
        }
        __syncthreads();
#pragma unroll
        for (int ks = 0; ks < 2; ks++) {
            int c = ks * 4 + quad;
            int ph = (c ^ (lrow & 7)) * 8;
            v8bf af[4], wf[4];
#pragma unroll
            for (int ms = 0; ms < 4; ms++)
                af[ms] = *(const v8bf*)&lA[(wm * 64 + ms * 16 + lrow) * 64 + ph];
#pragma unroll
            for (int ns = 0; ns < 4; ns++)
                wf[ns] = *(const v8bf*)&lW[(wn * 64 + ns * 16 + lrow) * 64 + ph];
#pragma unroll
            for (int ms = 0; ms < 4; ms++)
#pragma unroll
                for (int ns = 0; ns < 4; ns++)
                    acc[ms][ns] = __builtin_amdgcn_mfma_f32_16x16x32_bf16(
                        af[ms], wf[ns], acc[ms][ns], 0, 0, 0);
        }
    }

    u16* o16 = (u16*)out;
    float* o32 = (float*)out;

#pragma unroll
    for (int ms = 0; ms < 4; ms++) {
#pragma unroll
        for (int ns = 0; ns < 4; ns++) {
            int o_g = o0 + wn * 64 + ns * 16 + lrow;
            float bval = bf2f(bias[o_g]);
#pragma unroll
            for (int rg = 0; rg < 4; rg++) {
                int r_g = m0 + wm * 64 + ms * 16 + quad * 4 + rg;
                long oidx = (long)r_g * ldO + o_g;
                float v = acc[ms][ns][rg] + bval;
                if (mode == 0) {
                    o16[oidx] = f2bf(v);
                } else if (mode == 1) {
                    o16[oidx] = f2bf(gelu_exact(v));
                } else if (mode == 2) {
                    o16[oidx] = f2bf(v * bf2f(aux[oidx]));
                } else {
                    o32[oidx] = v;
                }
            }
        }
    }
}

// ---------- fused off/ml GEMM + online softmax + DCN interp ----------
// Block: 64 rows x 64 channels x branch z. Taps looped with online softmax.
// A (xg rows, K=256) persistent in regs; W streamed via LDS per tap.
// 32x32x16 MFMA: A m=lane&31, k=(lane>>5)*8+j; B n=lane&31, same k;
// C/D: col=lane&31, row=(reg&3)+8*(reg>>2)+4*(lane>>5)  [verified m74/m101]
__global__ __launch_bounds__(256, 2) void fused_dcn(
    const u16* __restrict__ xg,    // [4096][1536] interleaved
    const u16* __restrict__ vbuf,  // [4096][1536]
    const u16* __restrict__ Woff,  // [NP][KM*256][256], row o = c*K+k
    const u16* __restrict__ boff,  // [NP][KM*256]
    const u16* __restrict__ Wmw,
    const u16* __restrict__ bmw,
    u16* __restrict__ dcnb)        // [4096][1536]
{
    __shared__ alignas(16) u16 lsh[16384];   // 32KB: xg stage, then W stage

    const int i = blockIdx.z;
    const int K = 7 + 2 * i;
    const int r0 = blockIdx.x * 64;
    const int c0 = blockIdx.y * 64;
    const int tid = threadIdx.x;
    const int wave = tid >> 6, lane = tid & 63;
    const int wm = wave >> 1, wn = wave & 1;
    const int half = lane >> 5, l31 = lane & 31;

    const long brw = (long)i * (17 * 256) * 256;
    const u16* Wo = Woff + brw;
    const u16* Wmb = Wmw + brw;
    const u16* bo = boff + (long)i * (17 * 256);
    const u16* bmb = bmw + (long)i * (17 * 256);

    // stage xg rows r0..r0+63, transposed: lsh[chunk][row][8]
    {
        int cbase = wave * 8;
        for (int j = 0; j < 8; j++) {
            const u16* src = xg + (long)(r0 + lane) * 1536 + i * 256 + (cbase + j) * 8;
            gload16(src, &lsh[(cbase + j) * 512]);
        }
    }
    __syncthreads();
    // preload A-frags (persistent, reused for all taps & both tensors)
    v8bf af[16];
    {
        int row = wm * 32 + l31;
#pragma unroll
        for (int kb = 0; kb < 16; kb++) {
            int g = kb * 2 + half;
            af[kb] = *(const v8bf*)&lsh[g * 512 + row * 8];
        }
    }

    const int cg = c0 + wn * 32 + l31;       // this thread's channel
    const int l0 = (r0 & 511) + wm * 32;     // wave's base l (64-row blocks never straddle batches)
    const int bb = r0 >> 9;
    const u16* vbase = vbuf + (long)(bb * 512) * 1536 + i * 256 + cg;

    float m_[16], d_[16], a_[16];
#pragma unroll
    for (int e = 0; e < 16; e++) { m_[e] = -1e30f; d_[e] = 0.0f; a_[e] = 0.0f; }

    for (int k = 0; k < K; k++) {
        // ---- off GEMM tile ----
        __syncthreads();                      // lsh free (prev tap's reads done)
        {
            int cbase = wave * 8;
            for (int j = 0; j < 8; j++) {
                const u16* src = Wo + ((long)(c0 + lane) * K + k) * 256 + (cbase + j) * 8;
                gload16(src, &lsh[(cbase + j) * 512]);
            }
        }
        __syncthreads();
        v16f accO;
#pragma unroll
        for (int e = 0; e < 16; e++) accO[e] = 0.0f;
#pragma unroll
        for (int kb = 0; kb < 16; kb++) {
            int g = kb * 2 + half;
            v8bf bfr = *(const v8bf*)&lsh[g * 512 + (wn * 32 + l31) * 8];
            accO = __builtin_amdgcn_mfma_f32_32x32x16_bf16(af[kb], bfr, accO, 0, 0, 0);
        }
        // ---- ml GEMM tile ----
        __syncthreads();
        {
            int cbase = wave * 8;
            for (int j = 0; j < 8; j++) {
                const u16* src = Wmb + ((long)(c0 + lane) * K + k) * 256 + (cbase + j) * 8;
                gload16(src, &lsh[(cbase + j) * 512]);
            }
        }
        __syncthreads();
        v16f accM;
#pragma unroll
        for (int e = 0; e < 16; e++) accM[e] = 0.0f;
#pragma unroll
        for (int kb = 0; kb < 16; kb++) {
            int g = kb * 2 + half;
            v8bf bfr = *(const v8bf*)&lsh[g * 512 + (wn * 32 + l31) * 8];
            accM = __builtin_amdgcn_mfma_f32_32x32x16_bf16(af[kb], bfr, accM, 0, 0, 0);
        }
        // ---- online softmax + interp ----
        float bo_v = bf2f(bo[cg * K + k]);
        float bm_v = bf2f(bmb[cg * K + k]);
        float kc = (float)k - (float)(K - 1) * 0.5f;
#pragma unroll
        for (int e = 0; e < 16; e++) {
            int row = (e & 3) + 8 * (e >> 2) + 4 * half;
            float off = accO[e] + bo_v;
            float ml = accM[e] + bm_v;
            float mn = fmaxf(m_[e], ml);
            float alpha = __expf(m_[e] - mn);
            float we = __expf(ml - mn);
            float p = (float)(l0 + row) + kc + off;
            float p0 = floorf(p);
            float w = p - p0;
            int i0 = (int)p0;
            float v0 = 0.0f, v1 = 0.0f;
            if (i0 >= 0 && i0 < 512) v0 = bf2f(vbase[(long)i0 * 1536]);
            if (i0 + 1 >= 0 && i0 + 1 < 512) v1 = bf2f(vbase[(long)(i0 + 1) * 1536]);
            float itp = (1.0f - w) * v0 + w * v1;
            d_[e] = d_[e] * alpha + we;
            a_[e] = a_[e] * alpha + we * itp;
            m_[e] = mn;
        }
    }
    // epilogue
#pragma unroll
    for (int e = 0; e < 16; e++) {
        int row = (e & 3) + 8 * (e >> 2) + 4 * half;
        long r = (long)r0 + wm * 32 + row;
        dcnb[r * 1536 + i * 256 + cg] = f2bf(a_[e] / d_[e]);
    }
}

// ---------- residual + LayerNorm -> tn ----------
__global__ __launch_bounds__(256) void ln_kernel(
    const u16* __restrict__ xT, const float* __restrict__ res,
    const u16* __restrict__ ls, const u16* __restrict__ g, const u16* __restrict__ bb,
    u16* __restrict__ tnT)
{
    int r = blockIdx.x, c = threadIdx.x;
    long idx = (long)r * 256 + c;
    float y = bf2f(xT[idx]) + bf2f(ls[c]) * res[idx];

    __shared__ float red[8];
    int wave = c >> 6, lane = c & 63;
    float s = y;
#pragma unroll
    for (int m = 32; m; m >>= 1) s += __shfl_xor(s, m, 64);
    if (lane == 0) red[wave] = s;
    __syncthreads();
    float mu = (red[0] + red[1] + red[2] + red[3]) * (1.0f / 256.0f);
    float d = y - mu;
    float s2 = d * d;
#pragma unroll
    for (int m = 32; m; m >>= 1) s2 += __shfl_xor(s2, m, 64);
    if (lane == 0) red[4 + wave] = s2;
    __syncthreads();
    float var = (red[4] + red[5] + red[6] + red[7]) * (1.0f / 256.0f);
    float rstd = rsqrtf(var + 1e-6f);
    tnT[idx] = f2bf(d * rstd * bf2f(g[c]) + bf2f(bb[c]));
}

// ---------- final ----------
__global__ __launch_bounds__(256) void final_out(
    const float* __restrict__ x, const float* __restrict__ res, const u16* __restrict__ zT,
    const u16* __restrict__ ls, const u16* __restrict__ g2, float* __restrict__ out)
{
    __shared__ float tile[32][33];
    int b = blockIdx.z;
    int l0 = blockIdx.x * 32, c0 = blockIdx.y * 32;
    int tx = threadIdx.x & 31, ty = threadIdx.x >> 5;
#pragma unroll
    for (int j = 0; j < 4; j++) {
        int l = ty + j * 8;
        long ridx = ((long)b * 512 + l0 + l) * 256 + c0 + tx;
        int c = c0 + tx;
        float s = bf2f(ls[c]) * res[ridx] + bf2f(g2[c]) * bf2f(zT[ridx]);
        if (!(s > -0.04f && s < 0.04f)) s = 0.0f;
        tile[l][tx] = s;
    }
    __syncthreads();
#pragma unroll
    for (int j = 0; j < 4; j++) {
        int cc = ty + j * 8;
        long oidx = ((long)b * 256 + c0 + cc) * 512 + l0 + tx;
        out[oidx] = x[oidx] + tile[tx][cc];
    }
}

// ---------- launch ----------
extern "C" void kernel_launch(void* const* d_in, const int* in_sizes, int n_in,
                              void* d_out, int out_size, void* d_ws, size_t ws_size,
                              hipStream_t stream)
{
    const int Bz = 8, Cc = 256, Ll = 512, NP = 6, KM = 17, HID = 1024, Nr = 4096;
    const float* x = (const float*)d_in[0];

    void* base = nullptr;
    (void)hipGetSymbolAddress(&base, HIP_SYMBOL(g_ws));
    char* wsp = (char*)base;

    // arena: Wa Wvd Woff Wm Wod Wv Wp W1 W2 | ba bvd boff bm bod bv bp ls g2 lng lnb b1 b2
    static const int t_n[NT] = {
        393216, 393216, 6684672, 6684672, 393216, 393216, 393216, 262144, 262144,
        1536, 1536, 26112, 26112, 1536, 1536, 1536, 256, 256, 256, 256, 1024, 256
    };
    static const int t_src[NT] = {
        1, 3, 5, 7, 9, 11, 13, 19, 21,
        2, 4, 6, 8, 10, 12, 14, 15, 16, 17, 18, 20, 22
    };
    ConvArgs ca;
    unsigned int off = 0;
    int cum = 0;
    unsigned int t_off[NT];
    for (int t = 0; t < NT; t++) {
        ca.src[t] = (const float*)d_in[t_src[t]];
        ca.n[t] = t_n[t];
        ca.dstoff[t] = off;
        t_off[t] = off;
        ca.cumblk[t] = cum;
        off += (unsigned int)t_n[t];
        cum += (t_n[t] + 2047) / 2048;
    }
    ca.cumblk[NT] = cum;
    u16* arena = (u16*)wsp;
    size_t woff = ((size_t)off * 2 + 255) & ~(size_t)255;

    auto alloc = [&](size_t bytes) -> void* {
        void* p = wsp + woff;
        woff += (bytes + 255) & ~(size_t)255;
        return p;
    };
    const long NC = (long)Nr * Cc;
    const long NI = (long)Nr * 1536;
    u16*   xT   = (u16*)alloc(NC * 2);
    float* res  = (float*)alloc(NC * 4);
    u16*   xg   = (u16*)alloc(NI * 2);
    u16*   vv   = (u16*)alloc(NI * 2);
    u16*   vbuf = (u16*)alloc(NI * 2);
    u16*   dcnb = (u16*)alloc(NI * 2);
    u16*   tnT  = (u16*)alloc(NC * 2);
    u16*   hT   = (u16*)alloc((size_t)Nr * HID * 2);
    u16*   zT   = (u16*)alloc(NC * 2);
    u16*   Wp_p = (u16*)alloc((size_t)Cc * 1536 * 2);
    u16*   ubuf = xg;                        // xg dead before u-gemm

    u16* Wa_b  = arena + t_off[0];
    u16* Wvd_b = arena + t_off[1];
    u16* Wof_b = arena + t_off[2];
    u16* Wm_b  = arena + t_off[3];
    u16* Wod_b = arena + t_off[4];
    u16* Wv_b  = arena + t_off[5];
    u16* Wp_b  = arena + t_off[6];
    u16* W1_b  = arena + t_off[7];
    u16* W2_b  = arena + t_off[8];
    u16* ba_b  = arena + t_off[9];
    u16* bvd_b = arena + t_off[10];
    u16* bof_b = arena + t_off[11];
    u16* bm_b  = arena + t_off[12];
    u16* bod_b = arena + t_off[13];
    u16* bv_b  = arena + t_off[14];
    u16* bp_b  = arena + t_off[15];
    u16* ls_b  = arena + t_off[16];
    u16* g2_b  = arena + t_off[17];
    u16* lng_b = arena + t_off[18];
    u16* lnb_b = arena + t_off[19];
    u16* b1_b  = arena + t_off[20];
    u16* b2_b  = arena + t_off[21];

    const long CC2 = (long)Cc * Cc;

    // 0) convert + Wp permute
    conv_all<<<dim3(cum), 256, 0, stream>>>(ca, arena);
    permute_wp<<<dim3(Cc * 8), 256, 0, stream>>>(Wp_b, Wp_p);
    // 1) x -> xT
    transpose_f2b<<<dim3(Ll / 32, Cc / 32, Bz), 256, 0, stream>>>(x, xT, Cc, Ll);

    // 2) xg = gelu(xT.Wa^T+ba), vv = xT.Wv^T+bv (O=1536)
    gemm_t<<<dim3(Nr / 128, 1536 / 128, 1), 256, 0, stream>>>(
        xT, Cc, 0, Wa_b, Cc, 0, ba_b, 0, xg, 0,
        nullptr, nullptr, nullptr, nullptr, 0, Cc, 1536, 1);
    gemm_t<<<dim3(Nr / 128, 1536 / 128, 1), 256, 0, stream>>>(
        xT, Cc, 0, Wv_b, Cc, 0, bv_b, 0, vv, 0,
        nullptr, nullptr, nullptr, nullptr, 0, Cc, 1536, 0);
    // 3) v (z-batched)
    gemm_t<<<dim3(Nr / 128, Cc / 128, NP), 256, 0, stream>>>(
        xg, 1536, 256, Wvd_b, Cc, CC2, bvd_b, 256, vbuf, 512,
        nullptr, nullptr, nullptr, nullptr, 0, Cc, 1536, 0);

    // 4) fused off/ml GEMM + softmax + DCN (replaces 6 GEMMs + 6 DCN launches)
    fused_dcn<<<dim3(Nr / 64, Cc / 64, NP), 256, 0, stream>>>(
        xg, vbuf, Wof_b, bof_b, Wm_b, bm_b, dcnb);

    // 5) u (z-batched), p (K=1536 dense)
    gemm_t<<<dim3(Nr / 128, Cc / 128, NP), 256, 0, stream>>>(
        dcnb, 1536, 256, Wod_b, Cc, CC2, bod_b, 256, ubuf, 512,
        nullptr, nullptr, nullptr, vv, 256, Cc, 1536, 2);
    gemm_t<<<dim3(Nr / 128, Cc / 128, 1), 256, 0, stream>>>(
        ubuf, 1536, 0, Wp_p, 1536, 0, bp_b, 0, res, 0,
        nullptr, nullptr, nullptr, nullptr, 0, 1536, Cc, 3);

    // 6) LN + MLP
    ln_kernel<<<dim3(Nr), 256, 0, stream>>>(xT, res, ls_b, lng_b, lnb_b, tnT);
    gemm_t<<<dim3(Nr / 128, HID / 128, 1), 256, 0, stream>>>(
        tnT, Cc, 0, W1_b, Cc, 0, b1_b, 0, hT, 0,
        nullptr, nullptr, nullptr, nullptr, 0, Cc, HID, 1);
    gemm_t<<<dim3(Nr / 128, Cc / 128, 1), 256, 0, stream>>>(
        hT, HID, 0, W2_b, HID, 0, b2_b, 0, zT, 0,
        nullptr, nullptr, nullptr, nullptr, 0, HID, Cc, 0);
    // 7) final
    final_out<<<dim3(Ll / 32, Cc / 32, Bz), 256, 0, stream>>>(
        x, res, zT, ls_b, g2_b, (float*)d_out);
}